// Round 3
// baseline (147.171 us; speedup 1.0000x reference)
//
#include <hip/hip_runtime.h>
#include <cstddef>

#define TDIM 1024
#define SEQ 8192
#define NROWS 4096

typedef float f32x4 __attribute__((ext_vector_type(4)));

// One block per TABLE VALUE r (1024 blocks). out[row] depends only on
// cur[row], so rows sharing a cur value are identical: compute the row once
// in registers, then store it to every matching output row.
//   1. scan cur for rows with cur[row]==r  (16 KB broadcast read, L2-hot)
//   2. early-exit if none (~19/1024 blocks)
//   3. block-local histogram of his (LDS atomics; his kept in registers)
//   4. masked max + histogram-weighted exp-sum over 1024 table columns
//   5. prob table in LDS (reuses histogram buffer), gather once to regs
//   6. coalesced float4 stores to each matching row (same 128 MiB floor)
__global__ __launch_bounds__(256) void unique_fused_kernel(
    const int* __restrict__ his, const int* __restrict__ cur,
    const float* __restrict__ M, float* __restrict__ out)
{
    __shared__ int lc[TDIM];      // histogram, later reused as prob table
    __shared__ float red[8];      // [0..3] max partials, [4..7] sum partials
    __shared__ int mrows[NROWS];  // rows matching this block's r
    __shared__ int mcount;
    float* prob = (float*)lc;

    const int tid = threadIdx.x;
    const int r = blockIdx.x;     // table value owned by this block

    if (tid == 0) mcount = 0;
#pragma unroll
    for (int k = 0; k < 4; ++k) lc[tid + 256 * k] = 0;
    __syncthreads();

    // --- find matching output rows (cur is 16 KB, L2/LLC broadcast) ---
#pragma unroll
    for (int k = 0; k < 16; ++k) {
        int row = tid + 256 * k;
        if (cur[row] == r) {
            int idx = atomicAdd(&mcount, 1);
            mrows[idx] = row;
        }
    }

    // his into registers: int4 x 8 = 32 indices/thread (hist + gather reuse)
    const int4* his4 = (const int4*)his;       // 2048 int4
    int4 h[8];
#pragma unroll
    for (int it = 0; it < 8; ++it) h[it] = his4[it * 256 + tid];

    // M row for this block's value (uniform row, coalesced, L2-resident)
    const float* Mrow = M + (size_t)r * TDIM;
    float m[4];
#pragma unroll
    for (int k = 0; k < 4; ++k) m[k] = Mrow[tid + 256 * k];

    __syncthreads();
    const int nm = mcount;        // block-uniform
    if (nm == 0) return;          // value never occurs in cur

    // --- block-local histogram of his ---
#pragma unroll
    for (int it = 0; it < 8; ++it) {
        atomicAdd(&lc[h[it].x], 1);
        atomicAdd(&lc[h[it].y], 1);
        atomicAdd(&lc[h[it].z], 1);
        atomicAdd(&lc[h[it].w], 1);
    }
    __syncthreads();

    int c[4];
#pragma unroll
    for (int k = 0; k < 4; ++k) c[k] = lc[tid + 256 * k];

    // --- masked block max over table columns actually present in his ---
    float lmax = -3.402823466e38f;
#pragma unroll
    for (int k = 0; k < 4; ++k)
        if (c[k] > 0) lmax = fmaxf(lmax, m[k]);
#pragma unroll
    for (int off = 32; off > 0; off >>= 1)
        lmax = fmaxf(lmax, __shfl_down(lmax, off, 64));
    const int wave = tid >> 6, lane = tid & 63;
    if (lane == 0) red[wave] = lmax;
    __syncthreads();
    const float gmax = fmaxf(fmaxf(red[0], red[1]), fmaxf(red[2], red[3]));

    // --- histogram-weighted exp sum: sum_t c[t] * exp(M[r][t] - max) ---
    float e[4];
    float lsum = 0.f;
#pragma unroll
    for (int k = 0; k < 4; ++k) {
        e[k] = __expf(m[k] - gmax);
        lsum += (float)c[k] * e[k];
    }
#pragma unroll
    for (int off = 32; off > 0; off >>= 1)
        lsum += __shfl_down(lsum, off, 64);
    if (lane == 0) red[4 + wave] = lsum;
    __syncthreads();
    const float inv = 1.0f / (red[4] + red[5] + red[6] + red[7]);

    // --- prob table into LDS (overwrites histogram; c[] already in regs) ---
#pragma unroll
    for (int k = 0; k < 4; ++k)
        prob[tid + 256 * k] = e[k] * inv;
    __syncthreads();

    // --- gather ONCE into registers ---
    f32x4 o[8];
#pragma unroll
    for (int it = 0; it < 8; ++it) {
        o[it].x = prob[h[it].x];
        o[it].y = prob[h[it].y];
        o[it].z = prob[h[it].z];
        o[it].w = prob[h[it].w];
    }

    // --- store the row to every matching output row ---
    for (int mi = 0; mi < nm; ++mi) {
        int row = mrows[mi];                  // block-uniform broadcast
        f32x4* out4 = (f32x4*)(out + (size_t)row * SEQ);
#pragma unroll
        for (int it = 0; it < 8; ++it)
            out4[it * 256 + tid] = o[it];
    }
}

extern "C" void kernel_launch(void* const* d_in, const int* in_sizes, int n_in,
                              void* d_out, int out_size, void* d_ws, size_t ws_size,
                              hipStream_t stream) {
    const int*   his = (const int*)d_in[0];    // (8192,) int32 in [0,1024)
    const int*   cur = (const int*)d_in[1];    // (4096,) int32 in [0,1024)
    const float* M   = (const float*)d_in[2];  // (1024,1024) fp32
    float* out = (float*)d_out;                // (4096,8192) fp32
    (void)d_ws; (void)ws_size;

    unique_fused_kernel<<<TDIM, 256, 0, stream>>>(his, cur, M, out);
}

// Round 4
// 143.540 us; speedup vs baseline: 1.0253x; 1.0253x over previous
//
#include <hip/hip_runtime.h>
#include <cstddef>

#define TDIM 1024
#define SEQ 8192
#define NROWS 4096

typedef float f32x4 __attribute__((ext_vector_type(4)));

// One block per output row, NO histogram. Softmax statistics are computed
// directly on the gathered multiset:
//   max_j M[r][his[j]]  == masked max over present table columns
//   sum_j exp(..)       == histogram-weighted sum (multiplicity implicit)
// Phases: stage Mrow->LDS | gather 32 raw vals/thread | per-thread (m,s) |
// one fused butterfly (m,s) merge | cross-wave merge | scale+store from regs.
// 2 barriers, 1 LDS gather, zero LDS atomics.
__global__ __launch_bounds__(256) void fused_kernel(
    const int* __restrict__ his, const int* __restrict__ cur,
    const float* __restrict__ M, float* __restrict__ out)
{
    __shared__ float mrow[TDIM];
    __shared__ float redm[4];
    __shared__ float reds[4];

    const int tid = threadIdx.x;
    const int row = blockIdx.x;
    const int r = cur[row];                    // wave-uniform broadcast load
    const float* Mrow = M + (size_t)r * TDIM;

    // his into registers: int4 x 8 = 32 indices/thread (reused for output)
    const int4* his4 = (const int4*)his;       // 2048 int4
    int4 h[8];
#pragma unroll
    for (int it = 0; it < 8; ++it) h[it] = his4[it * 256 + tid];

    // stage M row into LDS (4 KB, coalesced, L2-resident source)
#pragma unroll
    for (int k = 0; k < 4; ++k) mrow[tid + 256 * k] = Mrow[tid + 256 * k];
    __syncthreads();

    // gather raw energies once into registers
    float g[32];
#pragma unroll
    for (int it = 0; it < 8; ++it) {
        g[4 * it + 0] = mrow[h[it].x];
        g[4 * it + 1] = mrow[h[it].y];
        g[4 * it + 2] = mrow[h[it].z];
        g[4 * it + 3] = mrow[h[it].w];
    }

    // per-thread max + exp-sum (e[] kept for the final store)
    float mloc = g[0];
#pragma unroll
    for (int j = 1; j < 32; ++j) mloc = fmaxf(mloc, g[j]);
    float e[32];
    float s = 0.f;
#pragma unroll
    for (int j = 0; j < 32; ++j) {
        e[j] = __expf(g[j] - mloc);
        s += e[j];
    }

    // fused (m,s) butterfly across the 64-lane wave
    float m = mloc;
#pragma unroll
    for (int off = 32; off > 0; off >>= 1) {
        float om = __shfl_xor(m, off, 64);
        float os = __shfl_xor(s, off, 64);
        float nm_ = fmaxf(m, om);
        s = s * __expf(m - nm_) + os * __expf(om - nm_);
        m = nm_;
    }

    // cross-wave merge via LDS (4 partial pairs)
    const int wave = tid >> 6, lane = tid & 63;
    if (lane == 0) { redm[wave] = m; reds[wave] = s; }
    __syncthreads();
    float M0 = redm[0], S0 = reds[0];
#pragma unroll
    for (int w = 1; w < 4; ++w) {
        float mw = redm[w], sw = reds[w];
        float nm_ = fmaxf(M0, mw);
        S0 = S0 * __expf(M0 - nm_) + sw * __expf(mw - nm_);
        M0 = nm_;
    }

    // single per-thread scale folds max-correction and normalization
    const float scale = __expf(mloc - M0) / S0;

    // coalesced float4 stores straight from registers
    f32x4* out4 = (f32x4*)(out + (size_t)row * SEQ);
#pragma unroll
    for (int it = 0; it < 8; ++it) {
        f32x4 o;
        o.x = e[4 * it + 0] * scale;
        o.y = e[4 * it + 1] * scale;
        o.z = e[4 * it + 2] * scale;
        o.w = e[4 * it + 3] * scale;
        out4[it * 256 + tid] = o;
    }
}

extern "C" void kernel_launch(void* const* d_in, const int* in_sizes, int n_in,
                              void* d_out, int out_size, void* d_ws, size_t ws_size,
                              hipStream_t stream) {
    const int*   his = (const int*)d_in[0];    // (8192,) int32 in [0,1024)
    const int*   cur = (const int*)d_in[1];    // (4096,) int32 in [0,1024)
    const float* M   = (const float*)d_in[2];  // (1024,1024) fp32
    float* out = (float*)d_out;                // (4096,8192) fp32
    (void)d_ws; (void)ws_size;

    fused_kernel<<<NROWS, 256, 0, stream>>>(his, cur, M, out);
}